// Round 15
// baseline (148.055 us; speedup 1.0000x reference)
//
#include <hip/hip_runtime.h>

typedef unsigned short u16;
typedef unsigned int u32;
typedef __attribute__((ext_vector_type(8))) short short8;
typedef __attribute__((ext_vector_type(4))) float f32x4;

#define DEV static __device__ __forceinline__

DEV float bf2f(u16 u){ u32 i = ((u32)u)<<16; float f; __builtin_memcpy(&f,&i,4); return f; }
DEV u16 f2bf(float f){ u32 i; __builtin_memcpy(&i,&f,4); u32 r = i + 0x7FFFu + ((i>>16)&1u); return (u16)(r>>16); }

DEV void gld16(const void* gp, void* lp){
  __builtin_amdgcn_global_load_lds((const __attribute__((address_space(1))) void*)gp,
                                   (__attribute__((address_space(3))) void*)lp, 16, 0, 0);
}

// ---------------- prep: x->bf16, 5 weight transposes, xpos table (one launch) ----------------
__global__ void k_prep(const float* __restrict__ x,
                       const float* __restrict__ Wq, const float* __restrict__ Wk,
                       const float* __restrict__ Wv, const float* __restrict__ Wg,
                       const float* __restrict__ Wo,
                       u16* __restrict__ xb, u16* __restrict__ WT, u16* __restrict__ WoT,
                       float4* __restrict__ tab){
  __shared__ float tile[32][33];
  int i = blockIdx.x, tid = threadIdx.x;
  if (i < 3072){
    size_t base = ((size_t)i*256 + tid)*4;
    float4 v = *(const float4*)(x + base);
    ushort4 o; o.x=f2bf(v.x); o.y=f2bf(v.y); o.z=f2bf(v.z); o.w=f2bf(v.w);
    *(ushort4*)(xb + base) = o;
  } else if (i < 7680){
    int j = i - 3072;
    const float* src; u16* dst; int N, K, bx, by;
    if (j < 576)       { src=Wq; dst=WT;             N=768;  K=768;  bx=j%24; by=j/24; }
    else if (j < 1152) { int q=j-576;  src=Wk; dst=WT+768ull*768;  N=768;  K=768;  bx=q%24; by=q/24; }
    else if (j < 2304) { int q=j-1152; src=Wv; dst=WT+1536ull*768; N=1536; K=768;  bx=q%48; by=q/48; }
    else if (j < 3456) { int q=j-2304; src=Wg; dst=WT+3072ull*768; N=1536; K=768;  bx=q%48; by=q/48; }
    else               { int q=j-3456; src=Wo; dst=WoT;            N=768;  K=1536; bx=q%24; by=q/24; }
    int n0 = bx*32, k0 = by*32;
    int tx = tid&31, ty = tid>>5;
    #pragma unroll
    for (int q=0;q<4;++q)
      tile[ty + q*8][tx] = src[(size_t)(k0 + ty + q*8)*N + n0 + tx];
    __syncthreads();
    #pragma unroll
    for (int q=0;q<4;++q)
      dst[(size_t)(n0 + ty + q*8)*K + k0 + tx] = f2bf(tile[tx][ty + q*8]);
  } else {
    int idx = (i-7680)*256 + tid;   // 2048*64
    int t = idx>>6, j = idx&63;
    float inv_freq = expf(-(float)j * (9.210340371976184f/64.f));
    float angle = (float)t * inv_freq;
    float zeta = (float)(j + 64) * (1.f/128.f);
    float decq = exp2f(log2f(zeta) * ((float)t*(1.f/512.f)));
    float deck = 1.f/decq;
    float sn, cs; sincosf(angle, &sn, &cs);
    float4 o; o.x = cs*decq; o.y = sn*decq; o.z = cs*deck; o.w = sn*deck;
    tab[idx] = o;
  }
}

// apply xPos to K only (sign -), in place; Q is rotated in-register inside passC
__global__ void k_xposK(u16* __restrict__ Kr, const float4* __restrict__ tab){
  int idx = blockIdx.x*256 + threadIdx.x;   // m*96 + h*16 + jg
  int jg = idx & 15;
  int h  = (idx>>4) % 6;
  int m  = (idx>>4) / 6;
  int t  = m & 2047;
  size_t base = (size_t)m*768 + h*128 + jg*4;
  ushort4 k1 = *(const ushort4*)(Kr + base);
  ushort4 k2 = *(const ushort4*)(Kr + base + 64);
  ushort4 ok1, ok2;
  const float4* tb = tab + t*64 + jg*4;
  #pragma unroll
  for (int jj=0;jj<4;++jj){
    float4 f = tb[jj];
    float a = bf2f(((const u16*)&k1)[jj]), b2 = bf2f(((const u16*)&k2)[jj]);
    ((u16*)&ok1)[jj] = f2bf(a*f.z - b2*f.w);
    ((u16*)&ok2)[jj] = f2bf(a*f.w + b2*f.z);
  }
  *(ushort4*)(Kr + base)      = ok1;
  *(ushort4*)(Kr + base + 64) = ok2;
}

// ---------------- merged V / K transposes ----------------
__global__ void k_trans(const u16* __restrict__ Vraw, u16* __restrict__ VbTs,
                        const u16* __restrict__ Kr, u16* __restrict__ KbT){
  __shared__ u16 tile[32][33];
  int i = blockIdx.x, tid = threadIdx.x;
  int tx = tid&31, ty = tid>>5;
  if (i < 6144){
    int bh = i>>9, r = i&511;
    int t0 = (r&63)*32, v0 = (r>>6)*32;
    int b = bh/6, h = bh%6;
    float lg2g = log2f(1.f - exp2f(-(float)(5+h)));
    float dec = exp2f(lg2g * (float)(63 - ((t0 + tx) & 63)));
    #pragma unroll
    for (int q=0;q<4;++q)
      tile[ty+q*8][tx] = Vraw[(size_t)(b*2048 + t0 + ty + q*8)*1536 + h*256 + v0 + tx];
    __syncthreads();
    #pragma unroll
    for (int q=0;q<4;++q)
      VbTs[(size_t)(bh*256 + v0 + ty + q*8)*2048 + t0 + tx] = f2bf(bf2f(tile[tx][ty+q*8]) * dec);
  } else {
    int j = i - 6144;
    int bh = j>>8, r = j&255;
    int t0 = (r&63)*32, d0 = (r>>6)*32;
    int b = bh/6, h = bh%6;
    #pragma unroll
    for (int q=0;q<4;++q)
      tile[ty+q*8][tx] = Kr[(size_t)(b*2048 + t0 + ty + q*8)*768 + h*128 + d0 + tx];
    __syncthreads();
    #pragma unroll
    for (int q=0;q<4;++q)
      KbT[(size_t)(bh*128 + d0 + ty + q*8)*2048 + t0 + tx] = tile[tx][ty+q*8];
  }
}

// ---------------- GEMM (round-4 proven structure) ----------------
template<int MODE, int BM>
__global__ __launch_bounds__(256)
void k_gemm(const u16* __restrict__ A, const u16* __restrict__ BT,
            int K, int N,
            u16* __restrict__ Qr, u16* __restrict__ Kr,
            u16* __restrict__ Vraw, u16* __restrict__ Gb,
            float* __restrict__ Out)
{
  constexpr int MR = BM/32;
  __shared__ u16 As[BM*64];
  __shared__ u16 Bs[128*64];
  const int tid = threadIdx.x;
  const int w = tid>>6, l = tid&63, g = l>>4, ln = l&15;
  const int wr = w>>1, wc = w&1;
  const int m0 = blockIdx.x*BM, n0 = blockIdx.y*128;
  const f32x4 fz = {0.f,0.f,0.f,0.f};
  f32x4 acc[MR][4];
  #pragma unroll
  for (int m=0;m<MR;++m)
    #pragma unroll
    for (int n=0;n<4;++n) acc[m][n] = fz;

  const int nk = K>>6;
  for (int kt=0; kt<nk; ++kt){
    const int k0 = kt<<6;
    #pragma unroll
    for (int i=0;i<BM/32;++i){
      int off = i*4096 + tid*16;
      int row = off>>7;
      int colb = (off&127) ^ ((row&7)<<4);
      gld16(A  + (size_t)(m0+row)*K + k0 + (colb>>1), (char*)As + i*4096 + w*1024);
    }
    #pragma unroll
    for (int i=0;i<4;++i){
      int off = i*4096 + tid*16;
      int row = off>>7;
      int colb = (off&127) ^ ((row&7)<<4);
      gld16(BT + (size_t)(n0+row)*K + k0 + (colb>>1), (char*)Bs + i*4096 + w*1024);
    }
    __syncthreads();
    #pragma unroll
    for (int kk=0;kk<2;++kk){
      short8 a[MR], b[4];
      #pragma unroll
      for (int m=0;m<MR;++m){
        int row = wr*(BM/2) + m*16 + ln;
        int byte = row*128 + ((kk*64 + g*16) ^ ((row&7)<<4));
        a[m] = *(const short8*)((const char*)As + byte);
      }
      #pragma unroll
      for (int n=0;n<4;++n){
        int row = wc*64 + n*16 + ln;
        int byte = row*128 + ((kk*64 + g*16) ^ ((row&7)<<4));
        b[n] = *(const short8*)((const char*)Bs + byte);
      }
      #pragma unroll
      for (int m=0;m<MR;++m)
        #pragma unroll
        for (int n=0;n<4;++n)
          acc[m][n] = __builtin_amdgcn_mfma_f32_16x16x32_bf16(a[m], b[n], acc[m][n], 0,0,0);
    }
    __syncthreads();
  }
  const int region = n0/768;
  #pragma unroll
  for (int m=0;m<MR;++m){
    int grow0 = m0 + wr*(BM/2) + m*16 + g*4;
    #pragma unroll
    for (int n=0;n<4;++n){
      int c = n0 + wc*64 + n*16 + ln;
      #pragma unroll
      for (int r=0;r<4;++r){
        float v = acc[m][n][r];
        size_t grow = (size_t)(grow0 + r);
        if (MODE == 1){
          Out[grow*(size_t)N + c] = v;
        } else {
          if (region==0)      Qr[grow*768 + c] = f2bf(v);
          else if (region==1) Kr[grow*768 + (c-768)] = f2bf(v);
          else if (region<4)  Vraw[grow*1536 + (c-1536)] = f2bf(v);
          else { float sg = v/(1.f+__expf(-v)); Gb[grow*1536 + (c-3072)] = f2bf(sg); }
        }
      }
    }
  }
}

// ---------------- pass A ----------------
__global__ __launch_bounds__(256)
void k_passA(const u16* __restrict__ VbTs, const u16* __restrict__ KbT, u16* __restrict__ Zb)
{
  __shared__ u16 Kt[128*64];
  __shared__ u16 Vt[256*64];
  const int tid = threadIdx.x, w = tid>>6, l = tid&63, g = l>>4, ln = l&15;
  const int c = blockIdx.x, bh = blockIdx.y;
  const f32x4 fz = {0.f,0.f,0.f,0.f};

  #pragma unroll
  for (int i=0;i<4;++i){
    int off = i*4096 + tid*16;
    int row = off>>7;
    int colb = (off&127) ^ ((row&7)<<4);
    gld16(KbT + (size_t)(bh*128 + row)*2048 + c*64 + (colb>>1), (char*)Kt + i*4096 + w*1024);
  }
  #pragma unroll
  for (int i=0;i<8;++i){
    int off = i*4096 + tid*16;
    int row = off>>7;
    int colb = (off&127) ^ ((row&7)<<4);
    gld16(VbTs + (size_t)(bh*256 + row)*2048 + c*64 + (colb>>1), (char*)Vt + i*4096 + w*1024);
  }
  __syncthreads();

  f32x4 acc[4][8];
  #pragma unroll
  for (int m=0;m<4;++m)
    #pragma unroll
    for (int n=0;n<8;++n) acc[m][n] = fz;

  #pragma unroll
  for (int kk=0;kk<2;++kk){
    short8 va[4], kb[8];
    #pragma unroll
    for (int m=0;m<4;++m){
      int vrow = w*64 + m*16 + ln;
      int byte = vrow*128 + ((kk*64 + g*16) ^ ((vrow&7)<<4));
      va[m] = *(const short8*)((const char*)Vt + byte);
    }
    #pragma unroll
    for (int n=0;n<8;++n){
      int krow = n*16 + ln;
      int byte = krow*128 + ((kk*64 + g*16) ^ ((krow&7)<<4));
      kb[n] = *(const short8*)((const char*)Kt + byte);
    }
    #pragma unroll
    for (int m=0;m<4;++m)
      #pragma unroll
      for (int n=0;n<8;++n)
        acc[m][n] = __builtin_amdgcn_mfma_f32_16x16x32_bf16(va[m], kb[n], acc[m][n], 0,0,0);
  }

  u16* z = Zb + (size_t)(c*12 + bh)*32768;
  #pragma unroll
  for (int m=0;m<4;++m)
    #pragma unroll
    for (int n=0;n<8;++n)
      #pragma unroll
      for (int r=0;r<4;++r){
        int v = w*64 + m*16 + g*4 + r;
        int d = n*16 + ln;
        z[v*128 + d] = f2bf(acc[m][n][r]);
      }
}

// ---------------- scan ----------------
__global__ __launch_bounds__(256)
void k_scan(const u16* __restrict__ Zb, u16* __restrict__ States)
{
  int gid = blockIdx.x*256 + threadIdx.x;
  int bh = gid >> 13;
  int e0 = (gid & 8191) * 4;
  const int h = bh % 6;
  const float lg2g = log2f(1.f - exp2f(-(float)(5+h)));
  const float gl = exp2f(lg2g * 64.f);
  ushort4 z[31];
  #pragma unroll
  for (int c=0;c<31;++c)
    z[c] = *(const ushort4*)(Zb + (size_t)(c*12 + bh)*32768 + e0);
  {
    ushort4 o; o.x=0;o.y=0;o.z=0;o.w=0;
    *(ushort4*)(States + (size_t)bh*32768 + e0) = o;
  }
  float S0=0.f,S1=0.f,S2=0.f,S3=0.f;
  #pragma unroll
  for (int c=1;c<32;++c){
    ushort4 zz = z[c-1];
    S0 = gl*S0 + bf2f(zz.x); S1 = gl*S1 + bf2f(zz.y);
    S2 = gl*S2 + bf2f(zz.z); S3 = gl*S3 + bf2f(zz.w);
    ushort4 o; o.x=f2bf(S0); o.y=f2bf(S1); o.z=f2bf(S2); o.w=f2bf(S3);
    *(ushort4*)(States + (size_t)(c*12 + bh)*32768 + e0) = o;
  }
}

// ---------------- pass C (v-split; Q rotated in-register on load) ----------------
__global__ __launch_bounds__(256)
void k_passC(const u16* __restrict__ Qb, const u16* __restrict__ Kb,
             const u16* __restrict__ VbTs, const u16* __restrict__ States,
             const float4* __restrict__ tab,
             u16* __restrict__ Ofb, float* __restrict__ partials)
{
  __shared__ u16 Ks[64*128];    // 16 KB
  __shared__ u16 Vt[128*64];    // 16 KB (this block's v-half)
  __shared__ float Ps[64*64];   // 16 KB
  __shared__ float red[8];
  const int tid = threadIdx.x, w = tid>>6, l = tid&63, g = l>>4, ln = l&15;
  const int cx = blockIdx.x, c = cx>>1, vh = cx&1;
  const int bh = blockIdx.y, b = bh/6, h = bh%6;
  const float omg = exp2f(-(float)(5+h));
  const float gamma = 1.f - omg;
  const float lg2g = log2f(gamma);
  const float scale = 0.08838834764831845f;
  const int q0 = c*64;
  const f32x4 fz = {0.f,0.f,0.f,0.f};

  short8 aq[4];
  {
    const size_t qrow = (size_t)(b*2048 + q0 + w*16 + ln)*768 + h*128;
    #pragma unroll
    for (int kk=0;kk<4;++kk) aq[kk] = *(const short8*)(Qb + qrow + kk*32 + g*8);
    // xPos Q rotation in-register: d = kk*32+g*8+jj pairs with d+64 = (kk+2)*32+g*8+jj
    const int tq = q0 + w*16 + ln;
    const float4* tb = tab + tq*64;
    #pragma unroll
    for (int kk=0;kk<2;++kk){
      #pragma unroll
      for (int jj=0;jj<8;++jj){
        float4 f = tb[kk*32 + g*8 + jj];
        float a1 = bf2f((u16)aq[kk][jj]), a2 = bf2f((u16)aq[kk+2][jj]);
        aq[kk][jj]   = (short)f2bf(a1*f.x - a2*f.y);
        aq[kk+2][jj] = (short)f2bf(a1*f.y + a2*f.x);
      }
    }
  }

  #pragma unroll
  for (int i=0;i<4;++i){
    int off = i*4096 + tid*16;
    int row = off>>8;
    int colb = (off&255) ^ ((row&7)<<4);
    gld16(Kb + (size_t)(b*2048 + q0 + row)*768 + h*128 + (colb>>1),
          (char*)Ks + i*4096 + w*1024);
  }
  #pragma unroll
  for (int i=0;i<4;++i){
    int off = i*4096 + tid*16;
    int row = off>>7;
    int colb = (off&127) ^ ((row&7)<<4);
    gld16(VbTs + (size_t)(bh*256 + vh*128 + row)*2048 + q0 + (colb>>1),
          (char*)Vt + i*4096 + w*1024);
  }
  __syncthreads();

  f32x4 sacc[4]; sacc[0]=fz; sacc[1]=fz; sacc[2]=fz; sacc[3]=fz;
  #pragma unroll
  for (int kk=0;kk<4;++kk){
    #pragma unroll
    for (int n=0;n<4;++n){
      int row = n*16 + ln;
      int byte = row*256 + ((kk*64 + g*16) ^ ((row&7)<<4));
      short8 bk = *(const short8*)((const char*)Ks + byte);
      sacc[n] = __builtin_amdgcn_mfma_f32_16x16x32_bf16(aq[kk], bk, sacc[n], 0,0,0);
    }
  }
  #pragma unroll
  for (int n=0;n<4;++n){
    int kj = n*16 + ln;
    #pragma unroll
    for (int r=0;r<4;++r){
      int a = w*16 + g*4 + r;
      float p = (a >= kj) ? sacc[n][r] : 0.f;
      int prow = w*16 + g*4 + r;
      int byte = prow*256 + ((((n*16+ln)*4)) ^ ((prow&7)<<4));
      *(float*)((char*)Ps + byte) = p;
    }
  }
  f32x4 acc[8];
  #pragma unroll
  for (int i=0;i<8;++i) acc[i] = fz;
  #pragma unroll
  for (int kk2=0;kk2<2;++kk2){
    int prow = w*16 + ln;
    int base = prow*256;
    int c0 = kk2*128 + g*32;
    int sw = (prow&7)<<4;
    f32x4 p0 = *(const f32x4*)((const char*)Ps + base + ((c0   )^sw));
    f32x4 p1 = *(const f32x4*)((const char*)Ps + base + ((c0+16)^sw));
    short8 ap;
    #pragma unroll
    for (int jj=0;jj<4;++jj){ ap[jj] = (short)f2bf(p0[jj]); ap[4+jj] = (short)f2bf(p1[jj]); }
    #pragma unroll
    for (int n2=0;n2<8;++n2){
      int vrow = n2*16 + ln;
      int byte = vrow*128 + ((kk2*64 + g*16) ^ ((vrow&7)<<4));
      short8 bv = *(const short8*)((const char*)Vt + byte);
      acc[n2] = __builtin_amdgcn_mfma_f32_16x16x32_bf16(ap, bv, acc[n2], 0,0,0);
    }
  }
  const float gi64 = exp2f(-64.f*lg2g);
  #pragma unroll
  for (int i=0;i<8;++i){ acc[i][0]*=gi64; acc[i][1]*=gi64; acc[i][2]*=gi64; acc[i][3]*=gi64; }
  const u16* st = States + (size_t)(c*12 + bh)*32768;
  #pragma unroll
  for (int kk=0;kk<4;++kk){
    #pragma unroll
    for (int n2=0;n2<8;++n2){
      short8 sb = *(const short8*)(st + (vh*128 + n2*16 + ln)*128 + kk*32 + g*8);
      acc[n2] = __builtin_amdgcn_mfma_f32_16x16x32_bf16(aq[kk], sb, acc[n2], 0,0,0);
    }
  }
  float rf[4];
  #pragma unroll
  for (int r=0;r<4;++r){
    int a = w*16 + g*4 + r;
    int qi = q0 + a;
    float rs = (1.f - exp2f(lg2g*(float)(qi+1))) / omg;
    rf[r] = scale * exp2f(lg2g*(float)(a+1)) * rsqrtf(fmaxf(rs, 1e-6f));
  }
  float lsum=0.f, lsq=0.f;
  #pragma unroll
  for (int n2=0;n2<8;++n2){
    #pragma unroll
    for (int r=0;r<4;++r){
      float v = acc[n2][r]*rf[r];
      Ofb[(size_t)(b*2048 + q0 + w*16 + g*4 + r)*1536 + h*256 + vh*128 + n2*16 + ln] = f2bf(v);
      lsum += v; lsq += v*v;
    }
  }
  #pragma unroll
  for (int o=32;o;o>>=1){ lsum += __shfl_xor(lsum,o,64); lsq += __shfl_xor(lsq,o,64); }
  if (l==0){ red[w*2]=lsum; red[w*2+1]=lsq; }
  __syncthreads();
  if (tid==0){
    partials[(cx*12+bh)*2]   = red[0]+red[2]+red[4]+red[6];
    partials[(cx*12+bh)*2+1] = red[1]+red[3]+red[5]+red[7];
  }
}

// ---------------- groupnorm + gate (bf16 Of; 64 partials per bh reduced in-kernel) ----------------
__global__ __launch_bounds__(256)
void k_gatenorm(const u16* __restrict__ Ofb, const u16* __restrict__ Gb,
                const float* __restrict__ gnw, const float* __restrict__ gnb,
                const float* __restrict__ partials, u16* __restrict__ Yb){
  const int bh = blockIdx.y, b = bh/6, h = bh%6;
  const int tid = threadIdx.x, l = tid&63;
  float s = partials[(l*12+bh)*2];
  float q = partials[(l*12+bh)*2+1];
  #pragma unroll
  for (int o=32;o;o>>=1){ s += __shfl_xor(s,o,64); q += __shfl_xor(q,o,64); }
  s = __shfl(s, 0, 64); q = __shfl(q, 0, 64);
  const float Ninv = 1.f/524288.f;
  float mean = s*Ninv;
  float var = q*Ninv - mean*mean;
  float rstd = rsqrtf(var + 1e-5f);

  int t = blockIdx.x*8 + (tid>>5);
  int v0 = (tid&31)*8;
  size_t base = (size_t)(b*2048 + t)*1536 + h*256 + v0;
  int cidx = h*256 + v0;
  short8 ov = *(const short8*)(Ofb + base);
  short8 gv = *(const short8*)(Gb + base);
  short8 yo;
  #pragma unroll
  for (int jj=0;jj<8;++jj){
    float o = bf2f((u16)ov[jj]);
    float nv = (o-mean)*rstd*gnw[cidx+jj] + gnb[cidx+jj];
    yo[jj] = (short)f2bf(nv * bf2f((u16)gv[jj]));
  }
  *(short8*)(Yb + base) = yo;
}

// ---------------- launch ----------------
extern "C" void kernel_launch(void* const* d_in, const int* in_sizes, int n_in,
                              void* d_out, int out_size, void* d_ws, size_t ws_size,
                              hipStream_t stream)
{
  const float* x   = (const float*)d_in[0];
  const float* Wq  = (const float*)d_in[1];
  const float* Wk  = (const float*)d_in[2];
  const float* Wv  = (const float*)d_in[3];
  const float* Wg  = (const float*)d_in[4];
  const float* Wo  = (const float*)d_in[5];
  const float* gnw = (const float*)d_in[6];
  const float* gnb = (const float*)d_in[7];
  float* out = (float*)d_out;

  char* ws = (char*)d_ws;
  u16*   xb     = (u16*)  (ws + 0);          // [prep -> gemm0]
  u16*   WT     = (u16*)  (ws + 6291456);    // [prep -> gemm0]
  u16*   Vraw   = (u16*)  (ws + 13369344);   // [gemm0 -> trans]
  u16*   KbT    = (u16*)  (ws + 6291456);    // [trans -> passA]   (over dead WT)
  u16*   States = (u16*)  (ws + 0);          // [scan -> passC]    (over dead xb)
  u16*   Yb     = (u16*)  (ws + 0);          // [gatenorm -> gemm1](over dead States)
  u16*   Kr     = (u16*)  (ws + 25952256);   // [gemm0 -> passC]
  u16*   Qr     = (u16*)  (ws + 32243712);   // [gemm0 -> passC]   (raw; rotated on load)
  u16*   Gb     = (u16*)  (ws + 38535168);   // [gemm0 -> gatenorm]
  u16*   WoT    = (u16*)  (ws + 51118080);   // [prep -> gemm1]
  u16*   VbTs   = (u16*)  (ws + 53477376);   // [trans -> passC]
  u16*   Zb     = (u16*)  (ws + 66060288);   // [passA -> scan]
  u16*   Ofb    = (u16*)  (ws + 66060288);   // [passC -> gatenorm] (over dead Zb)
  float* partials = (float*)(ws + 91226112); // [passC -> gatenorm]
  float4* tab   = (float4*)(ws + 95158272);  // [prep -> xposK/passC]

  k_prep<<<8192, 256, 0, stream>>>(x, Wq, Wk, Wv, Wg, Wo, xb, WT, WoT, tab);
  k_gemm<0,128><<<dim3(32,36), 256, 0, stream>>>(xb, WT, 768, 4608, Qr, Kr, Vraw, Gb, (float*)nullptr);
  k_xposK<<<1536, 256, 0, stream>>>(Kr, tab);
  k_trans<<<9216, 256, 0, stream>>>(Vraw, VbTs, Kr, KbT);
  k_passA<<<dim3(31,12), 256, 0, stream>>>(VbTs, KbT, Zb);
  k_scan<<<384, 256, 0, stream>>>(Zb, States);
  k_passC<<<dim3(64,12), 256, 0, stream>>>(Qr, Kr, VbTs, States, tab, Ofb, partials);
  k_gatenorm<<<dim3(256,12), 256, 0, stream>>>(Ofb, Gb, gnw, gnb, partials, Yb);
  k_gemm<1,64><<<dim3(64,6), 256, 0, stream>>>(Yb, WoT, 1536, 768,
                                            (u16*)nullptr,(u16*)nullptr,(u16*)nullptr,(u16*)nullptr,
                                            out);
}

// Round 16
// 142.922 us; speedup vs baseline: 1.0359x; 1.0359x over previous
//
#include <hip/hip_runtime.h>

typedef unsigned short u16;
typedef unsigned int u32;
typedef __attribute__((ext_vector_type(8))) short short8;
typedef __attribute__((ext_vector_type(4))) float f32x4;

#define DEV static __device__ __forceinline__

DEV float bf2f(u16 u){ u32 i = ((u32)u)<<16; float f; __builtin_memcpy(&f,&i,4); return f; }
DEV u16 f2bf(float f){ u32 i; __builtin_memcpy(&i,&f,4); u32 r = i + 0x7FFFu + ((i>>16)&1u); return (u16)(r>>16); }

DEV void gld16(const void* gp, void* lp){
  __builtin_amdgcn_global_load_lds((const __attribute__((address_space(1))) void*)gp,
                                   (__attribute__((address_space(3))) void*)lp, 16, 0, 0);
}

// ---------------- prep: x->bf16, 5 weight transposes, xpos table (one launch) ----------------
__global__ void k_prep(const float* __restrict__ x,
                       const float* __restrict__ Wq, const float* __restrict__ Wk,
                       const float* __restrict__ Wv, const float* __restrict__ Wg,
                       const float* __restrict__ Wo,
                       u16* __restrict__ xb, u16* __restrict__ WT, u16* __restrict__ WoT,
                       float4* __restrict__ tab){
  __shared__ float tile[32][33];
  int i = blockIdx.x, tid = threadIdx.x;
  if (i < 3072){
    size_t base = ((size_t)i*256 + tid)*4;
    float4 v = *(const float4*)(x + base);
    ushort4 o; o.x=f2bf(v.x); o.y=f2bf(v.y); o.z=f2bf(v.z); o.w=f2bf(v.w);
    *(ushort4*)(xb + base) = o;
  } else if (i < 7680){
    int j = i - 3072;
    const float* src; u16* dst; int N, K, bx, by;
    if (j < 576)       { src=Wq; dst=WT;             N=768;  K=768;  bx=j%24; by=j/24; }
    else if (j < 1152) { int q=j-576;  src=Wk; dst=WT+768ull*768;  N=768;  K=768;  bx=q%24; by=q/24; }
    else if (j < 2304) { int q=j-1152; src=Wv; dst=WT+1536ull*768; N=1536; K=768;  bx=q%48; by=q/48; }
    else if (j < 3456) { int q=j-2304; src=Wg; dst=WT+3072ull*768; N=1536; K=768;  bx=q%48; by=q/48; }
    else               { int q=j-3456; src=Wo; dst=WoT;            N=768;  K=1536; bx=q%24; by=q/24; }
    int n0 = bx*32, k0 = by*32;
    int tx = tid&31, ty = tid>>5;
    #pragma unroll
    for (int q=0;q<4;++q)
      tile[ty + q*8][tx] = src[(size_t)(k0 + ty + q*8)*N + n0 + tx];
    __syncthreads();
    #pragma unroll
    for (int q=0;q<4;++q)
      dst[(size_t)(n0 + ty + q*8)*K + k0 + tx] = f2bf(tile[tx][ty + q*8]);
  } else {
    int idx = (i-7680)*256 + tid;   // 2048*64
    int t = idx>>6, j = idx&63;
    float inv_freq = expf(-(float)j * (9.210340371976184f/64.f));
    float angle = (float)t * inv_freq;
    float zeta = (float)(j + 64) * (1.f/128.f);
    float decq = exp2f(log2f(zeta) * ((float)t*(1.f/512.f)));
    float deck = 1.f/decq;
    float sn, cs; sincosf(angle, &sn, &cs);
    float4 o; o.x = cs*decq; o.y = sn*decq; o.z = cs*deck; o.w = sn*deck;
    tab[idx] = o;
  }
}

// apply xPos to Q (sign +) and K (sign -) in place, 4 j's per thread
__global__ void k_xpos2(u16* __restrict__ Qr, u16* __restrict__ Kr, const float4* __restrict__ tab){
  int idx = blockIdx.x*256 + threadIdx.x;   // m*96 + h*16 + jg
  int jg = idx & 15;
  int h  = (idx>>4) % 6;
  int m  = (idx>>4) / 6;
  int t  = m & 2047;
  size_t base = (size_t)m*768 + h*128 + jg*4;
  ushort4 q1 = *(const ushort4*)(Qr + base);
  ushort4 q2 = *(const ushort4*)(Qr + base + 64);
  ushort4 k1 = *(const ushort4*)(Kr + base);
  ushort4 k2 = *(const ushort4*)(Kr + base + 64);
  ushort4 oq1, oq2, ok1, ok2;
  const float4* tb = tab + t*64 + jg*4;
  #pragma unroll
  for (int jj=0;jj<4;++jj){
    float4 f = tb[jj];
    float a, b2;
    a = bf2f(((const u16*)&q1)[jj]); b2 = bf2f(((const u16*)&q2)[jj]);
    ((u16*)&oq1)[jj] = f2bf(a*f.x - b2*f.y);
    ((u16*)&oq2)[jj] = f2bf(a*f.y + b2*f.x);
    a = bf2f(((const u16*)&k1)[jj]); b2 = bf2f(((const u16*)&k2)[jj]);
    ((u16*)&ok1)[jj] = f2bf(a*f.z - b2*f.w);
    ((u16*)&ok2)[jj] = f2bf(a*f.w + b2*f.z);
  }
  *(ushort4*)(Qr + base)      = oq1;
  *(ushort4*)(Qr + base + 64) = oq2;
  *(ushort4*)(Kr + base)      = ok1;
  *(ushort4*)(Kr + base + 64) = ok2;
}

// ---------------- merged V / K transposes ----------------
__global__ void k_trans(const u16* __restrict__ Vraw, u16* __restrict__ VbTs,
                        const u16* __restrict__ Kr, u16* __restrict__ KbT){
  __shared__ u16 tile[32][33];
  int i = blockIdx.x, tid = threadIdx.x;
  int tx = tid&31, ty = tid>>5;
  if (i < 6144){
    int bh = i>>9, r = i&511;
    int t0 = (r&63)*32, v0 = (r>>6)*32;
    int b = bh/6, h = bh%6;
    float lg2g = log2f(1.f - exp2f(-(float)(5+h)));
    float dec = exp2f(lg2g * (float)(63 - ((t0 + tx) & 63)));
    #pragma unroll
    for (int q=0;q<4;++q)
      tile[ty+q*8][tx] = Vraw[(size_t)(b*2048 + t0 + ty + q*8)*1536 + h*256 + v0 + tx];
    __syncthreads();
    #pragma unroll
    for (int q=0;q<4;++q)
      VbTs[(size_t)(bh*256 + v0 + ty + q*8)*2048 + t0 + tx] = f2bf(bf2f(tile[tx][ty+q*8]) * dec);
  } else {
    int j = i - 6144;
    int bh = j>>8, r = j&255;
    int t0 = (r&63)*32, d0 = (r>>6)*32;
    int b = bh/6, h = bh%6;
    #pragma unroll
    for (int q=0;q<4;++q)
      tile[ty+q*8][tx] = Kr[(size_t)(b*2048 + t0 + ty + q*8)*768 + h*128 + d0 + tx];
    __syncthreads();
    #pragma unroll
    for (int q=0;q<4;++q)
      KbT[(size_t)(bh*128 + d0 + ty + q*8)*2048 + t0 + tx] = tile[tx][ty+q*8];
  }
}

// ---------------- GEMM (round-4 proven structure) ----------------
template<int MODE, int BM>
__global__ __launch_bounds__(256)
void k_gemm(const u16* __restrict__ A, const u16* __restrict__ BT,
            int K, int N,
            u16* __restrict__ Qr, u16* __restrict__ Kr,
            u16* __restrict__ Vraw, u16* __restrict__ Gb,
            float* __restrict__ Out)
{
  constexpr int MR = BM/32;
  __shared__ u16 As[BM*64];
  __shared__ u16 Bs[128*64];
  const int tid = threadIdx.x;
  const int w = tid>>6, l = tid&63, g = l>>4, ln = l&15;
  const int wr = w>>1, wc = w&1;
  const int m0 = blockIdx.x*BM, n0 = blockIdx.y*128;
  const f32x4 fz = {0.f,0.f,0.f,0.f};
  f32x4 acc[MR][4];
  #pragma unroll
  for (int m=0;m<MR;++m)
    #pragma unroll
    for (int n=0;n<4;++n) acc[m][n] = fz;

  const int nk = K>>6;
  for (int kt=0; kt<nk; ++kt){
    const int k0 = kt<<6;
    #pragma unroll
    for (int i=0;i<BM/32;++i){
      int off = i*4096 + tid*16;
      int row = off>>7;
      int colb = (off&127) ^ ((row&7)<<4);
      gld16(A  + (size_t)(m0+row)*K + k0 + (colb>>1), (char*)As + i*4096 + w*1024);
    }
    #pragma unroll
    for (int i=0;i<4;++i){
      int off = i*4096 + tid*16;
      int row = off>>7;
      int colb = (off&127) ^ ((row&7)<<4);
      gld16(BT + (size_t)(n0+row)*K + k0 + (colb>>1), (char*)Bs + i*4096 + w*1024);
    }
    __syncthreads();
    #pragma unroll
    for (int kk=0;kk<2;++kk){
      short8 a[MR], b[4];
      #pragma unroll
      for (int m=0;m<MR;++m){
        int row = wr*(BM/2) + m*16 + ln;
        int byte = row*128 + ((kk*64 + g*16) ^ ((row&7)<<4));
        a[m] = *(const short8*)((const char*)As + byte);
      }
      #pragma unroll
      for (int n=0;n<4;++n){
        int row = wc*64 + n*16 + ln;
        int byte = row*128 + ((kk*64 + g*16) ^ ((row&7)<<4));
        b[n] = *(const short8*)((const char*)Bs + byte);
      }
      #pragma unroll
      for (int m=0;m<MR;++m)
        #pragma unroll
        for (int n=0;n<4;++n)
          acc[m][n] = __builtin_amdgcn_mfma_f32_16x16x32_bf16(a[m], b[n], acc[m][n], 0,0,0);
    }
    __syncthreads();
  }
  const int region = n0/768;
  #pragma unroll
  for (int m=0;m<MR;++m){
    int grow0 = m0 + wr*(BM/2) + m*16 + g*4;
    #pragma unroll
    for (int n=0;n<4;++n){
      int c = n0 + wc*64 + n*16 + ln;
      #pragma unroll
      for (int r=0;r<4;++r){
        float v = acc[m][n][r];
        size_t grow = (size_t)(grow0 + r);
        if (MODE == 1){
          Out[grow*(size_t)N + c] = v;
        } else {
          if (region==0)      Qr[grow*768 + c] = f2bf(v);
          else if (region==1) Kr[grow*768 + (c-768)] = f2bf(v);
          else if (region<4)  Vraw[grow*1536 + (c-1536)] = f2bf(v);
          else { float sg = v/(1.f+__expf(-v)); Gb[grow*1536 + (c-3072)] = f2bf(sg); }
        }
      }
    }
  }
}

// ---------------- pass A ----------------
__global__ __launch_bounds__(256)
void k_passA(const u16* __restrict__ VbTs, const u16* __restrict__ KbT, u16* __restrict__ Zb)
{
  __shared__ u16 Kt[128*64];
  __shared__ u16 Vt[256*64];
  const int tid = threadIdx.x, w = tid>>6, l = tid&63, g = l>>4, ln = l&15;
  const int c = blockIdx.x, bh = blockIdx.y;
  const f32x4 fz = {0.f,0.f,0.f,0.f};

  #pragma unroll
  for (int i=0;i<4;++i){
    int off = i*4096 + tid*16;
    int row = off>>7;
    int colb = (off&127) ^ ((row&7)<<4);
    gld16(KbT + (size_t)(bh*128 + row)*2048 + c*64 + (colb>>1), (char*)Kt + i*4096 + w*1024);
  }
  #pragma unroll
  for (int i=0;i<8;++i){
    int off = i*4096 + tid*16;
    int row = off>>7;
    int colb = (off&127) ^ ((row&7)<<4);
    gld16(VbTs + (size_t)(bh*256 + row)*2048 + c*64 + (colb>>1), (char*)Vt + i*4096 + w*1024);
  }
  __syncthreads();

  f32x4 acc[4][8];
  #pragma unroll
  for (int m=0;m<4;++m)
    #pragma unroll
    for (int n=0;n<8;++n) acc[m][n] = fz;

  #pragma unroll
  for (int kk=0;kk<2;++kk){
    short8 va[4], kb[8];
    #pragma unroll
    for (int m=0;m<4;++m){
      int vrow = w*64 + m*16 + ln;
      int byte = vrow*128 + ((kk*64 + g*16) ^ ((vrow&7)<<4));
      va[m] = *(const short8*)((const char*)Vt + byte);
    }
    #pragma unroll
    for (int n=0;n<8;++n){
      int krow = n*16 + ln;
      int byte = krow*128 + ((kk*64 + g*16) ^ ((krow&7)<<4));
      kb[n] = *(const short8*)((const char*)Kt + byte);
    }
    #pragma unroll
    for (int m=0;m<4;++m)
      #pragma unroll
      for (int n=0;n<8;++n)
        acc[m][n] = __builtin_amdgcn_mfma_f32_16x16x32_bf16(va[m], kb[n], acc[m][n], 0,0,0);
  }

  u16* z = Zb + (size_t)(c*12 + bh)*32768;
  #pragma unroll
  for (int m=0;m<4;++m)
    #pragma unroll
    for (int n=0;n<8;++n)
      #pragma unroll
      for (int r=0;r<4;++r){
        int v = w*64 + m*16 + g*4 + r;
        int d = n*16 + ln;
        z[v*128 + d] = f2bf(acc[m][n][r]);
      }
}

// ---------------- scan ----------------
__global__ __launch_bounds__(256)
void k_scan(const u16* __restrict__ Zb, u16* __restrict__ States)
{
  int gid = blockIdx.x*256 + threadIdx.x;
  int bh = gid >> 13;
  int e0 = (gid & 8191) * 4;
  const int h = bh % 6;
  const float lg2g = log2f(1.f - exp2f(-(float)(5+h)));
  const float gl = exp2f(lg2g * 64.f);
  ushort4 z[31];
  #pragma unroll
  for (int c=0;c<31;++c)
    z[c] = *(const ushort4*)(Zb + (size_t)(c*12 + bh)*32768 + e0);
  {
    ushort4 o; o.x=0;o.y=0;o.z=0;o.w=0;
    *(ushort4*)(States + (size_t)bh*32768 + e0) = o;
  }
  float S0=0.f,S1=0.f,S2=0.f,S3=0.f;
  #pragma unroll
  for (int c=1;c<32;++c){
    ushort4 zz = z[c-1];
    S0 = gl*S0 + bf2f(zz.x); S1 = gl*S1 + bf2f(zz.y);
    S2 = gl*S2 + bf2f(zz.z); S3 = gl*S3 + bf2f(zz.w);
    ushort4 o; o.x=f2bf(S0); o.y=f2bf(S1); o.z=f2bf(S2); o.w=f2bf(S3);
    *(ushort4*)(States + (size_t)(c*12 + bh)*32768 + e0) = o;
  }
}

// ---------------- pass C (v-split: grid (64,12), block = 64 q-rows x 128 v-cols) ----------------
__global__ __launch_bounds__(256)
void k_passC(const u16* __restrict__ Qb, const u16* __restrict__ Kb,
             const u16* __restrict__ VbTs, const u16* __restrict__ States,
             u16* __restrict__ Ofb, float* __restrict__ partials)
{
  __shared__ u16 Ks[64*128];    // 16 KB
  __shared__ u16 Vt[128*64];    // 16 KB (this block's v-half)
  __shared__ float Ps[64*64];   // 16 KB
  __shared__ float red[8];
  const int tid = threadIdx.x, w = tid>>6, l = tid&63, g = l>>4, ln = l&15;
  const int cx = blockIdx.x, c = cx>>1, vh = cx&1;
  const int bh = blockIdx.y, b = bh/6, h = bh%6;
  const float omg = exp2f(-(float)(5+h));
  const float gamma = 1.f - omg;
  const float lg2g = log2f(gamma);
  const float scale = 0.08838834764831845f;
  const int q0 = c*64;
  const f32x4 fz = {0.f,0.f,0.f,0.f};

  short8 aq[4];
  {
    const size_t qrow = (size_t)(b*2048 + q0 + w*16 + ln)*768 + h*128;
    #pragma unroll
    for (int kk=0;kk<4;++kk) aq[kk] = *(const short8*)(Qb + qrow + kk*32 + g*8);
  }

  #pragma unroll
  for (int i=0;i<4;++i){
    int off = i*4096 + tid*16;
    int row = off>>8;
    int colb = (off&255) ^ ((row&7)<<4);
    gld16(Kb + (size_t)(b*2048 + q0 + row)*768 + h*128 + (colb>>1),
          (char*)Ks + i*4096 + w*1024);
  }
  #pragma unroll
  for (int i=0;i<4;++i){
    int off = i*4096 + tid*16;
    int row = off>>7;
    int colb = (off&127) ^ ((row&7)<<4);
    gld16(VbTs + (size_t)(bh*256 + vh*128 + row)*2048 + q0 + (colb>>1),
          (char*)Vt + i*4096 + w*1024);
  }
  __syncthreads();

  f32x4 sacc[4]; sacc[0]=fz; sacc[1]=fz; sacc[2]=fz; sacc[3]=fz;
  #pragma unroll
  for (int kk=0;kk<4;++kk){
    #pragma unroll
    for (int n=0;n<4;++n){
      int row = n*16 + ln;
      int byte = row*256 + ((kk*64 + g*16) ^ ((row&7)<<4));
      short8 bk = *(const short8*)((const char*)Ks + byte);
      sacc[n] = __builtin_amdgcn_mfma_f32_16x16x32_bf16(aq[kk], bk, sacc[n], 0,0,0);
    }
  }
  #pragma unroll
  for (int n=0;n<4;++n){
    int kj = n*16 + ln;
    #pragma unroll
    for (int r=0;r<4;++r){
      int a = w*16 + g*4 + r;
      float p = (a >= kj) ? sacc[n][r] : 0.f;
      int prow = w*16 + g*4 + r;
      int byte = prow*256 + ((((n*16+ln)*4)) ^ ((prow&7)<<4));
      *(float*)((char*)Ps + byte) = p;
    }
  }
  f32x4 acc[8];
  #pragma unroll
  for (int i=0;i<8;++i) acc[i] = fz;
  #pragma unroll
  for (int kk2=0;kk2<2;++kk2){
    int prow = w*16 + ln;
    int base = prow*256;
    int c0 = kk2*128 + g*32;
    int sw = (prow&7)<<4;
    f32x4 p0 = *(const f32x4*)((const char*)Ps + base + ((c0   )^sw));
    f32x4 p1 = *(const f32x4*)((const char*)Ps + base + ((c0+16)^sw));
    short8 ap;
    #pragma unroll
    for (int jj=0;jj<4;++jj){ ap[jj] = (short)f2bf(p0[jj]); ap[4+jj] = (short)f2bf(p1[jj]); }
    #pragma unroll
    for (int n2=0;n2<8;++n2){
      int vrow = n2*16 + ln;
      int byte = vrow*128 + ((kk2*64 + g*16) ^ ((vrow&7)<<4));
      short8 bv = *(const short8*)((const char*)Vt + byte);
      acc[n2] = __builtin_amdgcn_mfma_f32_16x16x32_bf16(ap, bv, acc[n2], 0,0,0);
    }
  }
  const float gi64 = exp2f(-64.f*lg2g);
  #pragma unroll
  for (int i=0;i<8;++i){ acc[i][0]*=gi64; acc[i][1]*=gi64; acc[i][2]*=gi64; acc[i][3]*=gi64; }
  const u16* st = States + (size_t)(c*12 + bh)*32768;
  #pragma unroll
  for (int kk=0;kk<4;++kk){
    #pragma unroll
    for (int n2=0;n2<8;++n2){
      short8 sb = *(const short8*)(st + (vh*128 + n2*16 + ln)*128 + kk*32 + g*8);
      acc[n2] = __builtin_amdgcn_mfma_f32_16x16x32_bf16(aq[kk], sb, acc[n2], 0,0,0);
    }
  }
  float rf[4];
  #pragma unroll
  for (int r=0;r<4;++r){
    int a = w*16 + g*4 + r;
    int qi = q0 + a;
    float rs = (1.f - exp2f(lg2g*(float)(qi+1))) / omg;
    rf[r] = scale * exp2f(lg2g*(float)(a+1)) * rsqrtf(fmaxf(rs, 1e-6f));
  }
  float lsum=0.f, lsq=0.f;
  #pragma unroll
  for (int n2=0;n2<8;++n2){
    #pragma unroll
    for (int r=0;r<4;++r){
      float v = acc[n2][r]*rf[r];
      Ofb[(size_t)(b*2048 + q0 + w*16 + g*4 + r)*1536 + h*256 + vh*128 + n2*16 + ln] = f2bf(v);
      lsum += v; lsq += v*v;
    }
  }
  #pragma unroll
  for (int o=32;o;o>>=1){ lsum += __shfl_xor(lsum,o,64); lsq += __shfl_xor(lsq,o,64); }
  if (l==0){ red[w*2]=lsum; red[w*2+1]=lsq; }
  __syncthreads();
  if (tid==0){
    partials[(cx*12+bh)*2]   = red[0]+red[2]+red[4]+red[6];
    partials[(cx*12+bh)*2+1] = red[1]+red[3]+red[5]+red[7];
  }
}

// ---------------- groupnorm + gate (bf16 Of; 64 partials per bh reduced in-kernel) ----------------
__global__ __launch_bounds__(256)
void k_gatenorm(const u16* __restrict__ Ofb, const u16* __restrict__ Gb,
                const float* __restrict__ gnw, const float* __restrict__ gnb,
                const float* __restrict__ partials, u16* __restrict__ Yb){
  const int bh = blockIdx.y, b = bh/6, h = bh%6;
  const int tid = threadIdx.x, l = tid&63;
  float s = partials[(l*12+bh)*2];
  float q = partials[(l*12+bh)*2+1];
  #pragma unroll
  for (int o=32;o;o>>=1){ s += __shfl_xor(s,o,64); q += __shfl_xor(q,o,64); }
  s = __shfl(s, 0, 64); q = __shfl(q, 0, 64);
  const float Ninv = 1.f/524288.f;
  float mean = s*Ninv;
  float var = q*Ninv - mean*mean;
  float rstd = rsqrtf(var + 1e-5f);

  int t = blockIdx.x*8 + (tid>>5);
  int v0 = (tid&31)*8;
  size_t base = (size_t)(b*2048 + t)*1536 + h*256 + v0;
  int cidx = h*256 + v0;
  short8 ov = *(const short8*)(Ofb + base);
  short8 gv = *(const short8*)(Gb + base);
  short8 yo;
  #pragma unroll
  for (int jj=0;jj<8;++jj){
    float o = bf2f((u16)ov[jj]);
    float nv = (o-mean)*rstd*gnw[cidx+jj] + gnb[cidx+jj];
    yo[jj] = (short)f2bf(nv * bf2f((u16)gv[jj]));
  }
  *(short8*)(Yb + base) = yo;
}

// ---------------- launch ----------------
extern "C" void kernel_launch(void* const* d_in, const int* in_sizes, int n_in,
                              void* d_out, int out_size, void* d_ws, size_t ws_size,
                              hipStream_t stream)
{
  const float* x   = (const float*)d_in[0];
  const float* Wq  = (const float*)d_in[1];
  const float* Wk  = (const float*)d_in[2];
  const float* Wv  = (const float*)d_in[3];
  const float* Wg  = (const float*)d_in[4];
  const float* Wo  = (const float*)d_in[5];
  const float* gnw = (const float*)d_in[6];
  const float* gnb = (const float*)d_in[7];
  float* out = (float*)d_out;

  char* ws = (char*)d_ws;
  u16*   xb     = (u16*)  (ws + 0);          // [prep -> gemm0]
  u16*   WT     = (u16*)  (ws + 6291456);    // [prep -> gemm0]
  u16*   Vraw   = (u16*)  (ws + 13369344);   // [gemm0 -> trans]
  u16*   KbT    = (u16*)  (ws + 6291456);    // [trans -> passA]   (over dead WT)
  u16*   States = (u16*)  (ws + 0);          // [scan -> passC]    (over dead xb)
  u16*   Yb     = (u16*)  (ws + 0);          // [gatenorm -> gemm1](over dead States)
  u16*   Kr     = (u16*)  (ws + 25952256);   // [gemm0 -> passC]
  u16*   Qr     = (u16*)  (ws + 32243712);   // [gemm0 -> passC]
  u16*   Gb     = (u16*)  (ws + 38535168);   // [gemm0 -> gatenorm]
  u16*   WoT    = (u16*)  (ws + 51118080);   // [prep -> gemm1]
  u16*   VbTs   = (u16*)  (ws + 53477376);   // [trans -> passC]
  u16*   Zb     = (u16*)  (ws + 66060288);   // [passA -> scan]
  u16*   Ofb    = (u16*)  (ws + 66060288);   // [passC -> gatenorm] (over dead Zb)
  float* partials = (float*)(ws + 91226112); // [passC -> gatenorm]
  float4* tab   = (float4*)(ws + 95158272);  // [prep -> xpos2]

  k_prep<<<8192, 256, 0, stream>>>(x, Wq, Wk, Wv, Wg, Wo, xb, WT, WoT, tab);
  k_gemm<0,128><<<dim3(32,36), 256, 0, stream>>>(xb, WT, 768, 4608, Qr, Kr, Vraw, Gb, (float*)nullptr);
  k_xpos2<<<1536, 256, 0, stream>>>(Qr, Kr, tab);
  k_trans<<<9216, 256, 0, stream>>>(Vraw, VbTs, Kr, KbT);
  k_passA<<<dim3(31,12), 256, 0, stream>>>(VbTs, KbT, Zb);
  k_scan<<<384, 256, 0, stream>>>(Zb, States);
  k_passC<<<dim3(64,12), 256, 0, stream>>>(Qr, Kr, VbTs, States, Ofb, partials);
  k_gatenorm<<<dim3(256,12), 256, 0, stream>>>(Ofb, Gb, gnw, gnb, partials, Yb);
  k_gemm<1,64><<<dim3(64,6), 256, 0, stream>>>(Yb, WoT, 1536, 768,
                                            (u16*)nullptr,(u16*)nullptr,(u16*)nullptr,(u16*)nullptr,
                                            out);
}